// Round 7
// baseline (532.061 us; speedup 1.0000x reference)
//
#include <hip/hip_runtime.h>
#include <math.h>

#define Bn 128
#define Nn 1000
#define Tn 50
#define En 32000
#define Rn 4
#define FSn 43
#define NSELn 500
#define NFtot (Nn * FSn)   // 43000

// ---------------------------------------------------------------------------
// Mid conv chunk: conv1 (k=21, 3ch->3ch, bias+relu) for t in [T0, T0+8) via
// register scatter (each obs value read once), then conv2 (k=30 slice) into
// acc. T0/jlo are wave-uniform runtime; all y indices compile-time.
// ---------------------------------------------------------------------------
__device__ __forceinline__ void mid_chunk(const float* __restrict__ lds, int lane,
    int T0, int jlo,
    const float* __restrict__ w_m1, const float* __restrict__ w_m2,
    float bm0, float bm1v, float bm2, float* __restrict__ acc)
{
    float y0[8], y1[8], y2[8];
    #pragma unroll
    for (int j = 0; j < 8; ++j) { y0[j] = bm0; y1[j] = bm1v; y2[j] = bm2; }

    const int rb0 = (0 * 64 + lane) * 51 + T0;
    const int rb1 = (1 * 64 + lane) * 51 + T0;
    const int rb2 = (2 * 64 + lane) * 51 + T0;

    #pragma unroll
    for (int dt = 0; dt < 28; ++dt) {      // obs window [T0, T0+28)
        const float o0 = lds[rb0 + dt];
        const float o1 = lds[rb1 + dt];
        const float o2 = lds[rb2 + dt];
        #pragma unroll
        for (int j = 0; j < 8; ++j) {
            const int d = dt - j;          // compile-time per (dt,j)
            if (d >= 0 && d < 21) {
                y0[j] += o0 * w_m1[  0 + d] + o1 * w_m1[ 21 + d] + o2 * w_m1[ 42 + d];
                y1[j] += o0 * w_m1[ 63 + d] + o1 * w_m1[ 84 + d] + o2 * w_m1[105 + d];
                y2[j] += o0 * w_m1[126 + d] + o1 * w_m1[147 + d] + o2 * w_m1[168 + d];
            }
        }
    }
    #pragma unroll
    for (int j = 0; j < 8; ++j) {
        if (j >= jlo) {                    // uniform predicate (chunk overlap mask)
            const float u0 = fmaxf(y0[j], 0.f);
            const float u1 = fmaxf(y1[j], 0.f);
            const float u2 = fmaxf(y2[j], 0.f);
            const int tt = T0 + j;
            #pragma unroll
            for (int o = 0; o < 20; ++o) {
                acc[o] += u0 * w_m2[(o * 3 + 0) * 30 + tt]
                        + u1 * w_m2[(o * 3 + 1) * 30 + tt]
                        + u2 * w_m2[(o * 3 + 2) * 30 + tt];
            }
        }
    }
}

// ---------------------------------------------------------------------------
// Kernel 1: fused temporal features. 256 thr = 4 waves, 64 nodes per block.
// ROLE SPLIT (keeps per-wave live set < 64 VGPR -> no scratch; R6 regression
// was all-paths-per-wave with ~70 live floats at a 64-VGPR allocation):
//   w0: short conv t[0,24) sliding + long max t[0,25)    (+ biases)
//   w1: short conv t[24,48) sliding + long max t[25,50)
//   w2: mid conv t[0,16)  = scatter chunks T0=0,8        (+ biases)
//   w3: mid conv t[16,30) = scatter chunks T0=16, T0=22(jlo=2)
// Partials exchanged through the dead obs tile; w0 stores short+long, w2 mid.
// ---------------------------------------------------------------------------
__global__ __launch_bounds__(256, 4) void k_temporal(
    const float* __restrict__ obs,
    const float* __restrict__ w_s1, const float* __restrict__ b_s1,
    const float* __restrict__ w_s2, const float* __restrict__ b_s2,
    const float* __restrict__ w_m1, const float* __restrict__ b_m1,
    const float* __restrict__ w_m2, const float* __restrict__ b_m2,
    float* __restrict__ x)
{
    __shared__ float lds[3 * 64 * 51];

    const int b     = blockIdx.x;
    const int tile0 = blockIdx.y * 64;
    const int tid   = threadIdx.x;
    const int lane  = tid & 63;
    const int w     = __builtin_amdgcn_readfirstlane(tid >> 6);
    const int nrows = (Nn - tile0) < 64 ? (Nn - tile0) : 64;

    for (int c = 0; c < 3; ++c) {
        const float* srcp = obs + ((size_t)(b * 3 + c) * Nn + tile0) * Tn;
        for (int idx = tid; idx < nrows * Tn; idx += 256) {
            const int r = idx / Tn;
            const int t = idx - r * Tn;
            lds[(c * 64 + r) * 51 + t] = srcp[idx];
        }
    }
    __syncthreads();

    float acc[20];
    float mx0 = -1e30f, mx1 = -1e30f, mx2 = -1e30f;

    if (w < 2) {
        // ---------------- short path: t in [w*24, w*24+24) ----------------
        #pragma unroll
        for (int o = 0; o < 20; ++o) acc[o] = (w == 0) ? b_s2[o] : 0.f;

        const float s10 = b_s1[0], s11 = b_s1[1], s12 = b_s1[2];
        const int t0 = w * 24;
        const int base0 = (0 * 64 + lane) * 51 + t0;
        const int base1 = (1 * 64 + lane) * 51 + t0;
        const int base2 = (2 * 64 + lane) * 51 + t0;

        float a0 = lds[base0], p0 = lds[base0 + 1];
        float a1 = lds[base1], p1 = lds[base1 + 1];
        float a2 = lds[base2], p2 = lds[base2 + 1];

        #pragma unroll 3
        for (int t = 0; t < 24; ++t) {
            const float c0 = lds[base0 + t + 2];
            const float c1 = lds[base1 + t + 2];
            const float c2 = lds[base2 + t + 2];
            float v0 = s10 + a0 * w_s1[0]  + p0 * w_s1[1]  + c0 * w_s1[2]
                           + a1 * w_s1[3]  + p1 * w_s1[4]  + c1 * w_s1[5]
                           + a2 * w_s1[6]  + p2 * w_s1[7]  + c2 * w_s1[8];
            float v1 = s11 + a0 * w_s1[9]  + p0 * w_s1[10] + c0 * w_s1[11]
                           + a1 * w_s1[12] + p1 * w_s1[13] + c1 * w_s1[14]
                           + a2 * w_s1[15] + p2 * w_s1[16] + c2 * w_s1[17];
            float v2 = s12 + a0 * w_s1[18] + p0 * w_s1[19] + c0 * w_s1[20]
                           + a1 * w_s1[21] + p1 * w_s1[22] + c1 * w_s1[23]
                           + a2 * w_s1[24] + p2 * w_s1[25] + c2 * w_s1[26];
            v0 = fmaxf(v0, 0.f); v1 = fmaxf(v1, 0.f); v2 = fmaxf(v2, 0.f);
            const int tt = t0 + t;
            #pragma unroll
            for (int o = 0; o < 20; ++o) {
                acc[o] += v0 * w_s2[(o * 3 + 0) * 48 + tt]
                        + v1 * w_s2[(o * 3 + 1) * 48 + tt]
                        + v2 * w_s2[(o * 3 + 2) * 48 + tt];
            }
            a0 = p0; p0 = c0; a1 = p1; p1 = c1; a2 = p2; p2 = c2;
        }

        // ---------------- long path partial: t in [w*25, w*25+25) ----------
        const int rb0 = (0 * 64 + lane) * 51;
        const int rb1 = (1 * 64 + lane) * 51;
        const int rb2 = (2 * 64 + lane) * 51;
        const int l0 = w * 25;
        #pragma unroll 5
        for (int t = l0; t < l0 + 25; ++t) {
            mx0 = fmaxf(mx0, lds[rb0 + t]);
            mx1 = fmaxf(mx1, lds[rb1 + t]);
            mx2 = fmaxf(mx2, lds[rb2 + t]);
        }
    } else {
        // ---------------- mid path: two scatter chunks per wave -------------
        #pragma unroll
        for (int o = 0; o < 20; ++o) acc[o] = (w == 2) ? b_m2[o] : 0.f;
        const float m10 = b_m1[0], m11 = b_m1[1], m12 = b_m1[2];
        if (w == 2) {
            mid_chunk(lds, lane, 0,  0, w_m1, w_m2, m10, m11, m12, acc);
            mid_chunk(lds, lane, 8,  0, w_m1, w_m2, m10, m11, m12, acc);
        } else {
            mid_chunk(lds, lane, 16, 0, w_m1, w_m2, m10, m11, m12, acc);
            mid_chunk(lds, lane, 22, 2, w_m1, w_m2, m10, m11, m12, acc);
        }
    }

    // ---- exchange partials via the (now dead) obs tile ----
    __syncthreads();
    float* pshort = lds;               // [20][64]
    float* plong  = lds + 20 * 64;     // [3][64]
    float* pmid   = lds + 23 * 64;     // [20][64]

    if (w == 1) {
        #pragma unroll
        for (int o = 0; o < 20; ++o) pshort[o * 64 + lane] = acc[o];
        plong[0 * 64 + lane] = mx0;
        plong[1 * 64 + lane] = mx1;
        plong[2 * 64 + lane] = mx2;
    }
    if (w == 3) {
        #pragma unroll
        for (int o = 0; o < 20; ++o) pmid[o * 64 + lane] = acc[o];
    }
    __syncthreads();

    if (lane < nrows) {
        float* xp = x + ((size_t)b * Nn + tile0 + lane) * FSn;
        if (w == 0) {
            #pragma unroll
            for (int o = 0; o < 20; ++o)
                xp[o] = fmaxf(acc[o] + pshort[o * 64 + lane], 0.f);
            xp[40] = fmaxf(fmaxf(mx0, plong[0 * 64 + lane]), 0.f);
            xp[41] = fmaxf(fmaxf(mx1, plong[1 * 64 + lane]), 0.f);
            xp[42] = fmaxf(fmaxf(mx2, plong[2 * 64 + lane]), 0.f);
        } else if (w == 2) {
            #pragma unroll
            for (int o = 0; o < 20; ++o)
                xp[20 + o] = fmaxf(acc[o] + pmid[o * 64 + lane], 0.f);
        }
    }
}

// ---------------------------------------------------------------------------
// Transpose x[b][nf] (128 x 43000) -> xT[nf][b] (43000 x 128)
// ---------------------------------------------------------------------------
__global__ __launch_bounds__(256) void k_transpose(const float* __restrict__ x,
                                                   float* __restrict__ xT)
{
    __shared__ float tile[64][129];
    const int c0  = blockIdx.x * 64;
    const int tid = threadIdx.x;

    const int j  = tid & 63;
    const int bs = tid >> 6;
    for (int bb = bs; bb < Bn; bb += 4) {
        int c = c0 + j;
        if (c < NFtot) tile[j][bb] = x[(size_t)bb * NFtot + c];
    }
    __syncthreads();

    const int b  = tid & 127;
    for (int jj = (tid >> 7); jj < 64; jj += 2) {
        int c = c0 + jj;
        if (c < NFtot) xT[(size_t)c * Bn + b] = tile[jj][b];
    }
}

// ---------------------------------------------------------------------------
// CSR build
// ---------------------------------------------------------------------------
__global__ void k_zero(int* __restrict__ cnt, int* __restrict__ pos)
{
    int i = blockIdx.x * blockDim.x + threadIdx.x;
    if (i < 4096) { cnt[i] = 0; pos[i] = 0; }
}

__global__ void k_count(const int* __restrict__ ei, const int* __restrict__ et,
                        int* __restrict__ cnt)
{
    int e = blockIdx.x * blockDim.x + threadIdx.x;
    if (e < En) {
        int dst = ei[En + e];
        atomicAdd(&cnt[dst * Rn + et[e]], 1);
    }
}

__global__ __launch_bounds__(1024) void k_scan(const int* __restrict__ cnt,
                                               int* __restrict__ off)
{
    __shared__ int sums[1024];
    int tid = threadIdx.x;
    int base = tid * 4;
    int c[4];
    int ts = 0;
    #pragma unroll
    for (int k = 0; k < 4; ++k) {
        int i = base + k;
        c[k] = (i < Nn * Rn) ? cnt[i] : 0;
        ts += c[k];
    }
    sums[tid] = ts;
    __syncthreads();
    for (int d = 1; d < 1024; d <<= 1) {
        int t = 0;
        if (tid >= d) t = sums[tid - d];
        __syncthreads();
        sums[tid] += t;
        __syncthreads();
    }
    int excl = sums[tid] - ts;
    #pragma unroll
    for (int k = 0; k < 4; ++k) {
        int i = base + k;
        off[i] = excl;
        excl += c[k];
    }
}

__global__ void k_fill(const int* __restrict__ ei, const int* __restrict__ et,
                       const int* __restrict__ off, int* __restrict__ pos,
                       int* __restrict__ csr)
{
    int e = blockIdx.x * blockDim.x + threadIdx.x;
    if (e < En) {
        int src = ei[e];
        int dst = ei[En + e];
        int seg = dst * Rn + et[e];
        int p = atomicAdd(&pos[seg], 1);
        csr[off[seg] + p] = src;
    }
}

// ---------------------------------------------------------------------------
// Kernel 2a: per-(selected dst, relation) mean aggregation, float4 over b.
// grid = 500*4 blocks; 256 thr = 8 f-chunks x 32 b-quads.
// abar[i][r][f][b] = mean over edges of xT[src][f][b].
// ---------------------------------------------------------------------------
__global__ __launch_bounds__(256) void k_agg4(
    const float* __restrict__ xT,
    const int* __restrict__ csr, const int* __restrict__ off,
    const int* __restrict__ cnt, const int* __restrict__ sel,
    float* __restrict__ abar)
{
    __shared__ int srcs[128];

    const int blk = blockIdx.x;
    const int i   = blk >> 2;
    const int r   = blk & 3;
    const int dst = sel[i];
    const int tid = threadIdx.x;
    const int b4  = tid & 31;      // b quad index
    const int fc  = tid >> 5;      // 0..7

    const int seg = dst * Rn + r;
    const int c   = cnt[seg];
    const int o   = off[seg];
    const int cc  = (c < 128) ? c : 128;
    if (tid < cc) srcs[tid] = csr[o + tid];
    __syncthreads();

    const int nk = (fc < 3) ? 6 : 5;   // f = fc + 8k < 43

    float4 acc[6];
    #pragma unroll
    for (int k = 0; k < 6; ++k) acc[k] = make_float4(0.f, 0.f, 0.f, 0.f);

    const float4* xT4 = (const float4*)xT;
    for (int j = 0; j < cc; ++j) {
        const int src = srcs[j];
        const float4* base = xT4 + (size_t)src * (FSn * 32) + (size_t)fc * 32 + b4;
        #pragma unroll
        for (int k = 0; k < 6; ++k) {
            if (k < nk) {
                const float4 v = base[k * 8 * 32];
                acc[k].x += v.x; acc[k].y += v.y; acc[k].z += v.z; acc[k].w += v.w;
            }
        }
    }

    const float inv = (c > 0) ? 1.f / (float)c : 0.f;
    float4* ab4 = (float4*)abar + (size_t)(i * Rn + r) * (FSn * 32) + (size_t)fc * 32 + b4;
    #pragma unroll
    for (int k = 0; k < 6; ++k) {
        if (k < nk) {
            float4 v = acc[k];
            v.x *= inv; v.y *= inv; v.z *= inv; v.w *= inv;
            ab4[k * 8 * 32] = v;
        }
    }
}

// ---------------------------------------------------------------------------
// Kernel 2b: relational transform + root + leaky + final projection.
// grid = 500; 512 thr = 4 f-groups x 128 b. Reads abar + xT (root row).
// ---------------------------------------------------------------------------
__global__ __launch_bounds__(512) void k_trans(
    const float* __restrict__ xT, const float* __restrict__ abar,
    const float* __restrict__ w_rel, const float* __restrict__ w_root,
    const float* __restrict__ b_g,
    const float* __restrict__ w_fin, const float* __restrict__ b_fin,
    const float* __restrict__ la,
    const int* __restrict__ sel,
    float* __restrict__ logitT)
{
    __shared__ float red[FSn + 1][Bn];

    const int i   = blockIdx.x;
    const int dst = sel[i];
    const int tid = threadIdx.x;
    const int fs  = tid >> 7;
    const int b   = tid & 127;

    const int f0 = fs * 11;
    const int nf = (fs == 3) ? 10 : 11;

    float a[5][11];
    #pragma unroll
    for (int rr = 0; rr < 4; ++rr) {
        const float* ap = abar + ((size_t)(i * Rn + rr) * FSn + f0) * Bn + b;
        #pragma unroll
        for (int k = 0; k < 11; ++k)
            a[rr][k] = (k < nf) ? ap[(size_t)k * Bn] : 0.f;
    }
    {
        const float* xp = xT + ((size_t)dst * FSn + f0) * Bn + b;
        #pragma unroll
        for (int k = 0; k < 11; ++k)
            a[4][k] = (k < nf) ? xp[(size_t)k * Bn] : 0.f;
    }

    float accg[FSn];
    #pragma unroll
    for (int g = 0; g < FSn; ++g) accg[g] = 0.f;
    float psum = 0.f;

    #pragma unroll
    for (int k = 0; k < 11; ++k) {
        if (k < nf) {
            const int f = f0 + k;
            #pragma unroll
            for (int rr = 0; rr < 5; ++rr) {
                const float av = a[rr][k];
                const float* wrow = (rr < 4)
                    ? (w_rel + ((size_t)rr * FSn + f) * FSn)
                    : (w_root + (size_t)f * FSn);
                #pragma unroll
                for (int g = 0; g < FSn; ++g) accg[g] += av * wrow[g];
            }
            psum += a[4][k] * w_fin[1 + f];
        }
    }

    if (fs == 3) {
        #pragma unroll
        for (int g = 0; g < FSn; ++g) red[g][b] = accg[g];
        red[FSn][b] = psum;
    }
    __syncthreads();
    if (fs == 2) {
        #pragma unroll
        for (int g = 0; g < FSn; ++g) red[g][b] += accg[g];
        red[FSn][b] += psum;
    }
    __syncthreads();
    if (fs == 1) {
        #pragma unroll
        for (int g = 0; g < FSn; ++g) red[g][b] += accg[g];
        red[FSn][b] += psum;
    }
    __syncthreads();
    if (fs == 0) {
        float logit = b_fin[0] + w_fin[0] * la[(size_t)b * (NSELn + 1) + 1 + i]
                    + psum + red[FSn][b];
        #pragma unroll
        for (int g = 0; g < FSn; ++g) {
            float v = accg[g] + red[g][b] + b_g[g];
            v = (v > 0.f) ? v : 0.01f * v;
            logit += v * w_fin[44 + g];
        }
        logitT[(size_t)i * Bn + b] = logit;
    }
}

// ---------------------------------------------------------------------------
// Kernel 3: softmax over [0, logits(500)] per batch. Block per b.
// ---------------------------------------------------------------------------
__global__ __launch_bounds__(512) void k_softmax(const float* __restrict__ logitT,
                                                 float* __restrict__ out)
{
    __shared__ float red[512];
    const int b   = blockIdx.x;
    const int tid = threadIdx.x;

    const float l = (tid < NSELn) ? logitT[(size_t)tid * Bn + b] : -1e30f;
    red[tid] = l;
    __syncthreads();
    for (int s = 256; s > 0; s >>= 1) {
        if (tid < s) red[tid] = fmaxf(red[tid], red[tid + s]);
        __syncthreads();
    }
    const float m = fmaxf(red[0], 0.f);
    __syncthreads();

    const float e = (tid < NSELn) ? expf(l - m) : 0.f;
    red[tid] = e;
    __syncthreads();
    for (int s = 256; s > 0; s >>= 1) {
        if (tid < s) red[tid] += red[tid + s];
        __syncthreads();
    }
    const float e0  = expf(-m);
    const float inv = 1.f / (red[0] + e0);

    if (tid == 0) out[(size_t)b * (NSELn + 1)] = e0 * inv;
    if (tid < NSELn) out[(size_t)b * (NSELn + 1) + 1 + tid] = e * inv;
}

// ---------------------------------------------------------------------------
extern "C" void kernel_launch(void* const* d_in, const int* in_sizes, int n_in,
                              void* d_out, int out_size, void* d_ws, size_t ws_size,
                              hipStream_t stream)
{
    const float* obs    = (const float*)d_in[0];
    const float* la     = (const float*)d_in[1];
    const float* w_s1   = (const float*)d_in[2];
    const float* b_s1   = (const float*)d_in[3];
    const float* w_s2   = (const float*)d_in[4];
    const float* b_s2   = (const float*)d_in[5];
    const float* w_m1   = (const float*)d_in[6];
    const float* b_m1   = (const float*)d_in[7];
    const float* w_m2   = (const float*)d_in[8];
    const float* b_m2   = (const float*)d_in[9];
    const float* w_rel  = (const float*)d_in[10];
    const float* w_root = (const float*)d_in[11];
    const float* b_g    = (const float*)d_in[12];
    const float* w_fin  = (const float*)d_in[13];
    const float* b_fin  = (const float*)d_in[14];
    const int*   ei     = (const int*)d_in[15];
    const int*   et     = (const int*)d_in[16];
    const int*   sel    = (const int*)d_in[17];
    float*       out    = (float*)d_out;

    // workspace layout (x aliases the front of abar: x is dead before k_agg4
    // writes abar):
    //   abar : 500*4*43*128 = 11,008,000 floats (44 MB); x = first 5,504,000
    //   xT   : 5,504,000 floats (22 MB)
    //   cnt/off/pos : 4096 ints each;  csr : 32000 ints
    //   logitT : 500*128 floats
    float* abar   = (float*)d_ws;
    float* x      = abar;
    float* xT     = abar + 11008000;
    int*   cnt    = (int*)(xT + 5504000);
    int*   offb   = cnt + 4096;
    int*   pos    = offb + 4096;
    int*   csr    = pos + 4096;
    float* logitT = (float*)(csr + 32000);

    hipLaunchKernelGGL(k_zero,  dim3(16),  dim3(256), 0, stream, cnt, pos);
    hipLaunchKernelGGL(k_count, dim3((En + 255) / 256), dim3(256), 0, stream, ei, et, cnt);
    hipLaunchKernelGGL(k_scan,  dim3(1),   dim3(1024), 0, stream, cnt, offb);
    hipLaunchKernelGGL(k_fill,  dim3((En + 255) / 256), dim3(256), 0, stream, ei, et, offb, pos, csr);

    hipLaunchKernelGGL(k_temporal, dim3(Bn, (Nn + 63) / 64), dim3(256), 0, stream,
                       obs, w_s1, b_s1, w_s2, b_s2, w_m1, b_m1, w_m2, b_m2, x);

    hipLaunchKernelGGL(k_transpose, dim3((NFtot + 63) / 64), dim3(256), 0, stream, x, xT);

    hipLaunchKernelGGL(k_agg4, dim3(NSELn * Rn), dim3(256), 0, stream,
                       xT, csr, offb, cnt, sel, abar);

    hipLaunchKernelGGL(k_trans, dim3(NSELn), dim3(512), 0, stream,
                       xT, abar, w_rel, w_root, b_g, w_fin, b_fin, la, sel, logitT);

    hipLaunchKernelGGL(k_softmax, dim3(Bn), dim3(512), 0, stream, logitT, out);
}

// Round 8
// 345.071 us; speedup vs baseline: 1.5419x; 1.5419x over previous
//
#include <hip/hip_runtime.h>
#include <math.h>

#define Bn 128
#define Nn 1000
#define Tn 50
#define En 32000
#define Rn 4
#define FSn 43
#define NSELn 500
#define NFtot (Nn * FSn)   // 43000

// ---------------------------------------------------------------------------
// Kernel 1: fused temporal features. 256 thr = 4 waves, 64 nodes per block.
// ROLE SPLIT (R3 structure — the only variant that never spilled):
//   w0: short conv t[0,24) sliding + long max t[0,25)    (+ biases)
//   w1: short conv t[24,48) sliding + long max t[25,50)
//   w2: mid conv t[0,15)  (5 triples)                    (+ biases)
//   w3: mid conv t[15,30) (5 triples)
// Mid conv uses 9 NAMED SCALAR accumulators per 3-t triple (no arrays ->
// nothing the allocator can dump to scratch; R5/R6/R7 regression was the
// y[24]-array scatter spilling 0.3-0.6 GB). 23 LDS reads/ch/triple vs 63/t.
// ---------------------------------------------------------------------------
__global__ __launch_bounds__(256, 4) void k_temporal(
    const float* __restrict__ obs,
    const float* __restrict__ w_s1, const float* __restrict__ b_s1,
    const float* __restrict__ w_s2, const float* __restrict__ b_s2,
    const float* __restrict__ w_m1, const float* __restrict__ b_m1,
    const float* __restrict__ w_m2, const float* __restrict__ b_m2,
    float* __restrict__ x)
{
    __shared__ float lds[3 * 64 * 51];

    const int b     = blockIdx.x;
    const int tile0 = blockIdx.y * 64;
    const int tid   = threadIdx.x;
    const int lane  = tid & 63;
    const int w     = __builtin_amdgcn_readfirstlane(tid >> 6);
    const int nrows = (Nn - tile0) < 64 ? (Nn - tile0) : 64;

    for (int c = 0; c < 3; ++c) {
        const float* srcp = obs + ((size_t)(b * 3 + c) * Nn + tile0) * Tn;
        for (int idx = tid; idx < nrows * Tn; idx += 256) {
            const int r = idx / Tn;
            const int t = idx - r * Tn;
            lds[(c * 64 + r) * 51 + t] = srcp[idx];
        }
    }
    __syncthreads();

    const int rb0 = (0 * 64 + lane) * 51;
    const int rb1 = (1 * 64 + lane) * 51;
    const int rb2 = (2 * 64 + lane) * 51;

    float acc[20];
    float mx0 = -1e30f, mx1 = -1e30f, mx2 = -1e30f;

    if (w < 2) {
        // ---------------- short path: t in [w*24, w*24+24), sliding window ---
        #pragma unroll
        for (int o = 0; o < 20; ++o) acc[o] = (w == 0) ? b_s2[o] : 0.f;

        const float s10 = b_s1[0], s11 = b_s1[1], s12 = b_s1[2];
        const int t0 = w * 24;
        const int base0 = rb0 + t0;
        const int base1 = rb1 + t0;
        const int base2 = rb2 + t0;

        float a0 = lds[base0], p0 = lds[base0 + 1];
        float a1 = lds[base1], p1 = lds[base1 + 1];
        float a2 = lds[base2], p2 = lds[base2 + 1];

        #pragma unroll 3
        for (int t = 0; t < 24; ++t) {
            const float c0 = lds[base0 + t + 2];
            const float c1 = lds[base1 + t + 2];
            const float c2 = lds[base2 + t + 2];
            float v0 = s10 + a0 * w_s1[0]  + p0 * w_s1[1]  + c0 * w_s1[2]
                           + a1 * w_s1[3]  + p1 * w_s1[4]  + c1 * w_s1[5]
                           + a2 * w_s1[6]  + p2 * w_s1[7]  + c2 * w_s1[8];
            float v1 = s11 + a0 * w_s1[9]  + p0 * w_s1[10] + c0 * w_s1[11]
                           + a1 * w_s1[12] + p1 * w_s1[13] + c1 * w_s1[14]
                           + a2 * w_s1[15] + p2 * w_s1[16] + c2 * w_s1[17];
            float v2 = s12 + a0 * w_s1[18] + p0 * w_s1[19] + c0 * w_s1[20]
                           + a1 * w_s1[21] + p1 * w_s1[22] + c1 * w_s1[23]
                           + a2 * w_s1[24] + p2 * w_s1[25] + c2 * w_s1[26];
            v0 = fmaxf(v0, 0.f); v1 = fmaxf(v1, 0.f); v2 = fmaxf(v2, 0.f);
            const int tt = t0 + t;
            #pragma unroll
            for (int o = 0; o < 20; ++o) {
                acc[o] += v0 * w_s2[(o * 3 + 0) * 48 + tt]
                        + v1 * w_s2[(o * 3 + 1) * 48 + tt]
                        + v2 * w_s2[(o * 3 + 2) * 48 + tt];
            }
            a0 = p0; p0 = c0; a1 = p1; p1 = c1; a2 = p2; p2 = c2;
        }

        // ---------------- long path partial: t in [w*25, w*25+25) ----------
        const int l0 = w * 25;
        #pragma unroll 5
        for (int t = l0; t < l0 + 25; ++t) {
            mx0 = fmaxf(mx0, lds[rb0 + t]);
            mx1 = fmaxf(mx1, lds[rb1 + t]);
            mx2 = fmaxf(mx2, lds[rb2 + t]);
        }
    } else {
        // ---------------- mid path: t in [(w-2)*15, (w-2)*15+15) ------------
        // 5 triples of 3 t-outputs; 9 scalar conv1 accumulators per triple.
        #pragma unroll
        for (int o = 0; o < 20; ++o) acc[o] = (w == 2) ? b_m2[o] : 0.f;
        const float m10 = b_m1[0], m11 = b_m1[1], m12 = b_m1[2];
        const int tb = (w - 2) * 15;

        #pragma unroll 1
        for (int g = 0; g < 5; ++g) {
            const int t0 = tb + g * 3;
            float v00 = m10, v01 = m10, v02 = m10;
            float v10 = m11, v11 = m11, v12 = m11;
            float v20 = m12, v21 = m12, v22 = m12;

            #pragma unroll
            for (int dt = 0; dt < 23; ++dt) {
                const float q0 = lds[rb0 + t0 + dt];
                const float q1 = lds[rb1 + t0 + dt];
                const float q2 = lds[rb2 + t0 + dt];
                if (dt < 21) {              // tj = 0, d = dt
                    v00 += q0 * w_m1[  0 + dt] + q1 * w_m1[ 21 + dt] + q2 * w_m1[ 42 + dt];
                    v10 += q0 * w_m1[ 63 + dt] + q1 * w_m1[ 84 + dt] + q2 * w_m1[105 + dt];
                    v20 += q0 * w_m1[126 + dt] + q1 * w_m1[147 + dt] + q2 * w_m1[168 + dt];
                }
                if (dt >= 1 && dt < 22) {   // tj = 1, d = dt-1
                    const int d = dt - 1;
                    v01 += q0 * w_m1[  0 + d] + q1 * w_m1[ 21 + d] + q2 * w_m1[ 42 + d];
                    v11 += q0 * w_m1[ 63 + d] + q1 * w_m1[ 84 + d] + q2 * w_m1[105 + d];
                    v21 += q0 * w_m1[126 + d] + q1 * w_m1[147 + d] + q2 * w_m1[168 + d];
                }
                if (dt >= 2) {              // tj = 2, d = dt-2
                    const int d = dt - 2;
                    v02 += q0 * w_m1[  0 + d] + q1 * w_m1[ 21 + d] + q2 * w_m1[ 42 + d];
                    v12 += q0 * w_m1[ 63 + d] + q1 * w_m1[ 84 + d] + q2 * w_m1[105 + d];
                    v22 += q0 * w_m1[126 + d] + q1 * w_m1[147 + d] + q2 * w_m1[168 + d];
                }
            }

            const float u00 = fmaxf(v00, 0.f), u01 = fmaxf(v01, 0.f), u02 = fmaxf(v02, 0.f);
            const float u10 = fmaxf(v10, 0.f), u11 = fmaxf(v11, 0.f), u12 = fmaxf(v12, 0.f);
            const float u20 = fmaxf(v20, 0.f), u21 = fmaxf(v21, 0.f), u22 = fmaxf(v22, 0.f);

            #pragma unroll
            for (int o = 0; o < 20; ++o) {
                const float* w0 = w_m2 + (o * 3 + 0) * 30 + t0;
                const float* w1 = w_m2 + (o * 3 + 1) * 30 + t0;
                const float* w2 = w_m2 + (o * 3 + 2) * 30 + t0;
                acc[o] += u00 * w0[0] + u01 * w0[1] + u02 * w0[2]
                        + u10 * w1[0] + u11 * w1[1] + u12 * w1[2]
                        + u20 * w2[0] + u21 * w2[1] + u22 * w2[2];
            }
        }
    }

    // ---- exchange partials via the (now dead) obs tile ----
    __syncthreads();
    float* pshort = lds;               // [20][64]
    float* plong  = lds + 20 * 64;     // [3][64]
    float* pmid   = lds + 23 * 64;     // [20][64]

    if (w == 1) {
        #pragma unroll
        for (int o = 0; o < 20; ++o) pshort[o * 64 + lane] = acc[o];
        plong[0 * 64 + lane] = mx0;
        plong[1 * 64 + lane] = mx1;
        plong[2 * 64 + lane] = mx2;
    }
    if (w == 3) {
        #pragma unroll
        for (int o = 0; o < 20; ++o) pmid[o * 64 + lane] = acc[o];
    }
    __syncthreads();

    if (lane < nrows) {
        float* xp = x + ((size_t)b * Nn + tile0 + lane) * FSn;
        if (w == 0) {
            #pragma unroll
            for (int o = 0; o < 20; ++o)
                xp[o] = fmaxf(acc[o] + pshort[o * 64 + lane], 0.f);
            xp[40] = fmaxf(fmaxf(mx0, plong[0 * 64 + lane]), 0.f);
            xp[41] = fmaxf(fmaxf(mx1, plong[1 * 64 + lane]), 0.f);
            xp[42] = fmaxf(fmaxf(mx2, plong[2 * 64 + lane]), 0.f);
        } else if (w == 2) {
            #pragma unroll
            for (int o = 0; o < 20; ++o)
                xp[20 + o] = fmaxf(acc[o] + pmid[o * 64 + lane], 0.f);
        }
    }
}

// ---------------------------------------------------------------------------
// Transpose x[b][nf] (128 x 43000) -> xT[nf][b] (43000 x 128)
// ---------------------------------------------------------------------------
__global__ __launch_bounds__(256) void k_transpose(const float* __restrict__ x,
                                                   float* __restrict__ xT)
{
    __shared__ float tile[64][129];
    const int c0  = blockIdx.x * 64;
    const int tid = threadIdx.x;

    const int j  = tid & 63;
    const int bs = tid >> 6;
    for (int bb = bs; bb < Bn; bb += 4) {
        int c = c0 + j;
        if (c < NFtot) tile[j][bb] = x[(size_t)bb * NFtot + c];
    }
    __syncthreads();

    const int b  = tid & 127;
    for (int jj = (tid >> 7); jj < 64; jj += 2) {
        int c = c0 + jj;
        if (c < NFtot) xT[(size_t)c * Bn + b] = tile[jj][b];
    }
}

// ---------------------------------------------------------------------------
// CSR build
// ---------------------------------------------------------------------------
__global__ void k_zero(int* __restrict__ cnt, int* __restrict__ pos)
{
    int i = blockIdx.x * blockDim.x + threadIdx.x;
    if (i < 4096) { cnt[i] = 0; pos[i] = 0; }
}

__global__ void k_count(const int* __restrict__ ei, const int* __restrict__ et,
                        int* __restrict__ cnt)
{
    int e = blockIdx.x * blockDim.x + threadIdx.x;
    if (e < En) {
        int dst = ei[En + e];
        atomicAdd(&cnt[dst * Rn + et[e]], 1);
    }
}

__global__ __launch_bounds__(1024) void k_scan(const int* __restrict__ cnt,
                                               int* __restrict__ off)
{
    __shared__ int sums[1024];
    int tid = threadIdx.x;
    int base = tid * 4;
    int c[4];
    int ts = 0;
    #pragma unroll
    for (int k = 0; k < 4; ++k) {
        int i = base + k;
        c[k] = (i < Nn * Rn) ? cnt[i] : 0;
        ts += c[k];
    }
    sums[tid] = ts;
    __syncthreads();
    for (int d = 1; d < 1024; d <<= 1) {
        int t = 0;
        if (tid >= d) t = sums[tid - d];
        __syncthreads();
        sums[tid] += t;
        __syncthreads();
    }
    int excl = sums[tid] - ts;
    #pragma unroll
    for (int k = 0; k < 4; ++k) {
        int i = base + k;
        off[i] = excl;
        excl += c[k];
    }
}

__global__ void k_fill(const int* __restrict__ ei, const int* __restrict__ et,
                       const int* __restrict__ off, int* __restrict__ pos,
                       int* __restrict__ csr)
{
    int e = blockIdx.x * blockDim.x + threadIdx.x;
    if (e < En) {
        int src = ei[e];
        int dst = ei[En + e];
        int seg = dst * Rn + et[e];
        int p = atomicAdd(&pos[seg], 1);
        csr[off[seg] + p] = src;
    }
}

// ---------------------------------------------------------------------------
// Kernel 2a: per-(selected dst, relation) mean aggregation, float4 over b.
// grid = 500*4 blocks; 256 thr = 8 f-chunks x 32 b-quads.
// abar[i][r][f][b] = mean over edges of xT[src][f][b].
// ---------------------------------------------------------------------------
__global__ __launch_bounds__(256) void k_agg4(
    const float* __restrict__ xT,
    const int* __restrict__ csr, const int* __restrict__ off,
    const int* __restrict__ cnt, const int* __restrict__ sel,
    float* __restrict__ abar)
{
    __shared__ int srcs[128];

    const int blk = blockIdx.x;
    const int i   = blk >> 2;
    const int r   = blk & 3;
    const int dst = sel[i];
    const int tid = threadIdx.x;
    const int b4  = tid & 31;      // b quad index
    const int fc  = tid >> 5;      // 0..7

    const int seg = dst * Rn + r;
    const int c   = cnt[seg];
    const int o   = off[seg];
    const int cc  = (c < 128) ? c : 128;
    if (tid < cc) srcs[tid] = csr[o + tid];
    __syncthreads();

    const int nk = (fc < 3) ? 6 : 5;   // f = fc + 8k < 43

    float4 acc[6];
    #pragma unroll
    for (int k = 0; k < 6; ++k) acc[k] = make_float4(0.f, 0.f, 0.f, 0.f);

    const float4* xT4 = (const float4*)xT;
    for (int j = 0; j < cc; ++j) {
        const int src = srcs[j];
        const float4* base = xT4 + (size_t)src * (FSn * 32) + (size_t)fc * 32 + b4;
        #pragma unroll
        for (int k = 0; k < 6; ++k) {
            if (k < nk) {
                const float4 v = base[k * 8 * 32];
                acc[k].x += v.x; acc[k].y += v.y; acc[k].z += v.z; acc[k].w += v.w;
            }
        }
    }

    const float inv = (c > 0) ? 1.f / (float)c : 0.f;
    float4* ab4 = (float4*)abar + (size_t)(i * Rn + r) * (FSn * 32) + (size_t)fc * 32 + b4;
    #pragma unroll
    for (int k = 0; k < 6; ++k) {
        if (k < nk) {
            float4 v = acc[k];
            v.x *= inv; v.y *= inv; v.z *= inv; v.w *= inv;
            ab4[k * 8 * 32] = v;
        }
    }
}

// ---------------------------------------------------------------------------
// Kernel 2b: relational transform + root + leaky + final projection.
// grid = 500; 512 thr = 4 f-groups x 128 b. Reads abar + xT (root row).
// ---------------------------------------------------------------------------
__global__ __launch_bounds__(512) void k_trans(
    const float* __restrict__ xT, const float* __restrict__ abar,
    const float* __restrict__ w_rel, const float* __restrict__ w_root,
    const float* __restrict__ b_g,
    const float* __restrict__ w_fin, const float* __restrict__ b_fin,
    const float* __restrict__ la,
    const int* __restrict__ sel,
    float* __restrict__ logitT)
{
    __shared__ float red[FSn + 1][Bn];

    const int i   = blockIdx.x;
    const int dst = sel[i];
    const int tid = threadIdx.x;
    const int fs  = tid >> 7;
    const int b   = tid & 127;

    const int f0 = fs * 11;
    const int nf = (fs == 3) ? 10 : 11;

    float a[5][11];
    #pragma unroll
    for (int rr = 0; rr < 4; ++rr) {
        const float* ap = abar + ((size_t)(i * Rn + rr) * FSn + f0) * Bn + b;
        #pragma unroll
        for (int k = 0; k < 11; ++k)
            a[rr][k] = (k < nf) ? ap[(size_t)k * Bn] : 0.f;
    }
    {
        const float* xp = xT + ((size_t)dst * FSn + f0) * Bn + b;
        #pragma unroll
        for (int k = 0; k < 11; ++k)
            a[4][k] = (k < nf) ? xp[(size_t)k * Bn] : 0.f;
    }

    float accg[FSn];
    #pragma unroll
    for (int g = 0; g < FSn; ++g) accg[g] = 0.f;
    float psum = 0.f;

    #pragma unroll
    for (int k = 0; k < 11; ++k) {
        if (k < nf) {
            const int f = f0 + k;
            #pragma unroll
            for (int rr = 0; rr < 5; ++rr) {
                const float av = a[rr][k];
                const float* wrow = (rr < 4)
                    ? (w_rel + ((size_t)rr * FSn + f) * FSn)
                    : (w_root + (size_t)f * FSn);
                #pragma unroll
                for (int g = 0; g < FSn; ++g) accg[g] += av * wrow[g];
            }
            psum += a[4][k] * w_fin[1 + f];
        }
    }

    if (fs == 3) {
        #pragma unroll
        for (int g = 0; g < FSn; ++g) red[g][b] = accg[g];
        red[FSn][b] = psum;
    }
    __syncthreads();
    if (fs == 2) {
        #pragma unroll
        for (int g = 0; g < FSn; ++g) red[g][b] += accg[g];
        red[FSn][b] += psum;
    }
    __syncthreads();
    if (fs == 1) {
        #pragma unroll
        for (int g = 0; g < FSn; ++g) red[g][b] += accg[g];
        red[FSn][b] += psum;
    }
    __syncthreads();
    if (fs == 0) {
        float logit = b_fin[0] + w_fin[0] * la[(size_t)b * (NSELn + 1) + 1 + i]
                    + psum + red[FSn][b];
        #pragma unroll
        for (int g = 0; g < FSn; ++g) {
            float v = accg[g] + red[g][b] + b_g[g];
            v = (v > 0.f) ? v : 0.01f * v;
            logit += v * w_fin[44 + g];
        }
        logitT[(size_t)i * Bn + b] = logit;
    }
}

// ---------------------------------------------------------------------------
// Kernel 3: softmax over [0, logits(500)] per batch. Block per b.
// ---------------------------------------------------------------------------
__global__ __launch_bounds__(512) void k_softmax(const float* __restrict__ logitT,
                                                 float* __restrict__ out)
{
    __shared__ float red[512];
    const int b   = blockIdx.x;
    const int tid = threadIdx.x;

    const float l = (tid < NSELn) ? logitT[(size_t)tid * Bn + b] : -1e30f;
    red[tid] = l;
    __syncthreads();
    for (int s = 256; s > 0; s >>= 1) {
        if (tid < s) red[tid] = fmaxf(red[tid], red[tid + s]);
        __syncthreads();
    }
    const float m = fmaxf(red[0], 0.f);
    __syncthreads();

    const float e = (tid < NSELn) ? expf(l - m) : 0.f;
    red[tid] = e;
    __syncthreads();
    for (int s = 256; s > 0; s >>= 1) {
        if (tid < s) red[tid] += red[tid + s];
        __syncthreads();
    }
    const float e0  = expf(-m);
    const float inv = 1.f / (red[0] + e0);

    if (tid == 0) out[(size_t)b * (NSELn + 1)] = e0 * inv;
    if (tid < NSELn) out[(size_t)b * (NSELn + 1) + 1 + tid] = e * inv;
}

// ---------------------------------------------------------------------------
extern "C" void kernel_launch(void* const* d_in, const int* in_sizes, int n_in,
                              void* d_out, int out_size, void* d_ws, size_t ws_size,
                              hipStream_t stream)
{
    const float* obs    = (const float*)d_in[0];
    const float* la     = (const float*)d_in[1];
    const float* w_s1   = (const float*)d_in[2];
    const float* b_s1   = (const float*)d_in[3];
    const float* w_s2   = (const float*)d_in[4];
    const float* b_s2   = (const float*)d_in[5];
    const float* w_m1   = (const float*)d_in[6];
    const float* b_m1   = (const float*)d_in[7];
    const float* w_m2   = (const float*)d_in[8];
    const float* b_m2   = (const float*)d_in[9];
    const float* w_rel  = (const float*)d_in[10];
    const float* w_root = (const float*)d_in[11];
    const float* b_g    = (const float*)d_in[12];
    const float* w_fin  = (const float*)d_in[13];
    const float* b_fin  = (const float*)d_in[14];
    const int*   ei     = (const int*)d_in[15];
    const int*   et     = (const int*)d_in[16];
    const int*   sel    = (const int*)d_in[17];
    float*       out    = (float*)d_out;

    // workspace layout (x aliases the front of abar: x is dead before k_agg4
    // writes abar):
    //   abar : 500*4*43*128 = 11,008,000 floats (44 MB); x = first 5,504,000
    //   xT   : 5,504,000 floats (22 MB)
    //   cnt/off/pos : 4096 ints each;  csr : 32000 ints
    //   logitT : 500*128 floats
    float* abar   = (float*)d_ws;
    float* x      = abar;
    float* xT     = abar + 11008000;
    int*   cnt    = (int*)(xT + 5504000);
    int*   offb   = cnt + 4096;
    int*   pos    = offb + 4096;
    int*   csr    = pos + 4096;
    float* logitT = (float*)(csr + 32000);

    hipLaunchKernelGGL(k_zero,  dim3(16),  dim3(256), 0, stream, cnt, pos);
    hipLaunchKernelGGL(k_count, dim3((En + 255) / 256), dim3(256), 0, stream, ei, et, cnt);
    hipLaunchKernelGGL(k_scan,  dim3(1),   dim3(1024), 0, stream, cnt, offb);
    hipLaunchKernelGGL(k_fill,  dim3((En + 255) / 256), dim3(256), 0, stream, ei, et, offb, pos, csr);

    hipLaunchKernelGGL(k_temporal, dim3(Bn, (Nn + 63) / 64), dim3(256), 0, stream,
                       obs, w_s1, b_s1, w_s2, b_s2, w_m1, b_m1, w_m2, b_m2, x);

    hipLaunchKernelGGL(k_transpose, dim3((NFtot + 63) / 64), dim3(256), 0, stream, x, xT);

    hipLaunchKernelGGL(k_agg4, dim3(NSELn * Rn), dim3(256), 0, stream,
                       xT, csr, offb, cnt, sel, abar);

    hipLaunchKernelGGL(k_trans, dim3(NSELn), dim3(512), 0, stream,
                       xT, abar, w_rel, w_root, b_g, w_fin, b_fin, la, sel, logitT);

    hipLaunchKernelGGL(k_softmax, dim3(Bn), dim3(512), 0, stream, logitT, out);
}

// Round 9
// 283.954 us; speedup vs baseline: 1.8738x; 1.2152x over previous
//
#include <hip/hip_runtime.h>
#include <math.h>

#define Bn 128
#define Nn 1000
#define Tn 50
#define En 32000
#define Rn 4
#define FSn 43
#define NSELn 500
#define NFtot (Nn * FSn)   // 43000

// ---------------------------------------------------------------------------
// Kernel 1: fused temporal features. 512 thr = 8 waves, 64 nodes per block.
// R3's EXACT inner-loop bodies (the only codegen measured good: 52 VGPR, no
// spill) with 2x finer role split for full occupancy:
//   w0..w3: short conv quarter t[w*12,(w+1)*12) + long-max quarter
//   w4..w7: mid conv quarter of [0,30)
// LDS 39 KB -> 4 blocks/CU x 8 waves = 32 waves/CU (vs R3's 16).
// Partials: waves 1-3 write [23][64], waves 5-7 write [20][64] into the dead
// obs tile (33 KB); w0 reduces short+long, w4 reduces mid.
// ---------------------------------------------------------------------------
__global__ __launch_bounds__(512) void k_temporal(
    const float* __restrict__ obs,
    const float* __restrict__ w_s1, const float* __restrict__ b_s1,
    const float* __restrict__ w_s2, const float* __restrict__ b_s2,
    const float* __restrict__ w_m1, const float* __restrict__ b_m1,
    const float* __restrict__ w_m2, const float* __restrict__ b_m2,
    float* __restrict__ x)
{
    __shared__ float lds[3 * 64 * 51];

    const int b     = blockIdx.x;
    const int tile0 = blockIdx.y * 64;
    const int tid   = threadIdx.x;
    const int lane  = tid & 63;
    const int w     = __builtin_amdgcn_readfirstlane(tid >> 6);   // 0..7
    const int nrows = (Nn - tile0) < 64 ? (Nn - tile0) : 64;

    for (int c = 0; c < 3; ++c) {
        const float* srcp = obs + ((size_t)(b * 3 + c) * Nn + tile0) * Tn;
        for (int idx = tid; idx < nrows * Tn; idx += 512) {
            const int r = idx / Tn;
            const int t = idx - r * Tn;
            lds[(c * 64 + r) * 51 + t] = srcp[idx];
        }
    }
    __syncthreads();

    float acc[20];
    float mx0 = -1e30f, mx1 = -1e30f, mx2 = -1e30f;

    if (w < 4) {
        // ---------------- short path: t in [w*12, w*12+12) ----------------
        #pragma unroll
        for (int o = 0; o < 20; ++o) acc[o] = (w == 0) ? b_s2[o] : 0.f;

        const float s10 = b_s1[0], s11 = b_s1[1], s12 = b_s1[2];
        const int t0 = w * 12;

        #pragma unroll 1
        for (int t = t0; t < t0 + 12; ++t) {
            float ov[9];
            #pragma unroll
            for (int c = 0; c < 3; ++c)
                #pragma unroll
                for (int d = 0; d < 3; ++d)
                    ov[c * 3 + d] = lds[(c * 64 + lane) * 51 + t + d];

            float v0 = s10, v1 = s11, v2 = s12;
            #pragma unroll
            for (int c = 0; c < 3; ++c) {
                v0 += ov[c * 3 + 0] * w_s1[(0 * 3 + c) * 3 + 0]
                    + ov[c * 3 + 1] * w_s1[(0 * 3 + c) * 3 + 1]
                    + ov[c * 3 + 2] * w_s1[(0 * 3 + c) * 3 + 2];
                v1 += ov[c * 3 + 0] * w_s1[(1 * 3 + c) * 3 + 0]
                    + ov[c * 3 + 1] * w_s1[(1 * 3 + c) * 3 + 1]
                    + ov[c * 3 + 2] * w_s1[(1 * 3 + c) * 3 + 2];
                v2 += ov[c * 3 + 0] * w_s1[(2 * 3 + c) * 3 + 0]
                    + ov[c * 3 + 1] * w_s1[(2 * 3 + c) * 3 + 1]
                    + ov[c * 3 + 2] * w_s1[(2 * 3 + c) * 3 + 2];
            }
            v0 = fmaxf(v0, 0.f); v1 = fmaxf(v1, 0.f); v2 = fmaxf(v2, 0.f);
            #pragma unroll
            for (int o = 0; o < 20; ++o) {
                acc[o] += v0 * w_s2[(o * 3 + 0) * 48 + t]
                        + v1 * w_s2[(o * 3 + 1) * 48 + t]
                        + v2 * w_s2[(o * 3 + 2) * 48 + t];
            }
        }

        // ---------------- long path quarter: t in [w*50/4, (w+1)*50/4) ------
        const int rb0 = (0 * 64 + lane) * 51;
        const int rb1 = (1 * 64 + lane) * 51;
        const int rb2 = (2 * 64 + lane) * 51;
        const int l0 = (w * 50) >> 2;
        const int l1 = ((w + 1) * 50) >> 2;
        #pragma unroll 1
        for (int t = l0; t < l1; ++t) {
            mx0 = fmaxf(mx0, lds[rb0 + t]);
            mx1 = fmaxf(mx1, lds[rb1 + t]);
            mx2 = fmaxf(mx2, lds[rb2 + t]);
        }
    } else {
        // ---------------- mid path: t in [m*30/4, (m+1)*30/4), m=w-4 --------
        #pragma unroll
        for (int o = 0; o < 20; ++o) acc[o] = (w == 4) ? b_m2[o] : 0.f;

        const float m10 = b_m1[0], m11 = b_m1[1], m12 = b_m1[2];
        const int m  = w - 4;
        const int t0 = (m * 30) >> 2;        // 0,7,15,22
        const int t1 = ((m + 1) * 30) >> 2;  // 7,15,22,30

        #pragma unroll 1
        for (int t = t0; t < t1; ++t) {
            float v0 = m10, v1 = m11, v2 = m12;
            #pragma unroll
            for (int c = 0; c < 3; ++c) {
                const int base = (c * 64 + lane) * 51 + t;
                #pragma unroll
                for (int d = 0; d < 21; ++d) {
                    const float ov = lds[base + d];
                    v0 += ov * w_m1[(0 * 3 + c) * 21 + d];
                    v1 += ov * w_m1[(1 * 3 + c) * 21 + d];
                    v2 += ov * w_m1[(2 * 3 + c) * 21 + d];
                }
            }
            v0 = fmaxf(v0, 0.f); v1 = fmaxf(v1, 0.f); v2 = fmaxf(v2, 0.f);
            #pragma unroll
            for (int o = 0; o < 20; ++o) {
                acc[o] += v0 * w_m2[(o * 3 + 0) * 30 + t]
                        + v1 * w_m2[(o * 3 + 1) * 30 + t]
                        + v2 * w_m2[(o * 3 + 2) * 30 + t];
            }
        }
    }

    // ---- exchange partials via the (now dead) obs tile ----
    // regions: waves 1-3 -> [23][64] each at (w-1)*1472 (20 short + 3 long)
    //          waves 5-7 -> [20][64] each at 4416 + (w-5)*1280
    __syncthreads();
    if (w >= 1 && w <= 3) {
        float* r = lds + (w - 1) * 1472 + lane;
        #pragma unroll
        for (int o = 0; o < 20; ++o) r[o * 64] = acc[o];
        r[20 * 64] = mx0;
        r[21 * 64] = mx1;
        r[22 * 64] = mx2;
    } else if (w >= 5) {
        float* r = lds + 4416 + (w - 5) * 1280 + lane;
        #pragma unroll
        for (int o = 0; o < 20; ++o) r[o * 64] = acc[o];
    }
    __syncthreads();

    if (lane < nrows) {
        float* xp = x + ((size_t)b * Nn + tile0 + lane) * FSn;
        if (w == 0) {
            #pragma unroll
            for (int o = 0; o < 20; ++o) {
                const int a = o * 64 + lane;
                xp[o] = fmaxf(acc[o] + lds[a] + lds[1472 + a] + lds[2944 + a], 0.f);
            }
            {
                const int a0 = 20 * 64 + lane, a1 = 21 * 64 + lane, a2 = 22 * 64 + lane;
                xp[40] = fmaxf(fmaxf(fmaxf(mx0, lds[a0]), fmaxf(lds[1472 + a0], lds[2944 + a0])), 0.f);
                xp[41] = fmaxf(fmaxf(fmaxf(mx1, lds[a1]), fmaxf(lds[1472 + a1], lds[2944 + a1])), 0.f);
                xp[42] = fmaxf(fmaxf(fmaxf(mx2, lds[a2]), fmaxf(lds[1472 + a2], lds[2944 + a2])), 0.f);
            }
        } else if (w == 4) {
            #pragma unroll
            for (int o = 0; o < 20; ++o) {
                const int a = 4416 + o * 64 + lane;
                xp[20 + o] = fmaxf(acc[o] + lds[a] + lds[a + 1280] + lds[a + 2560], 0.f);
            }
        }
    }
}

// ---------------------------------------------------------------------------
// Transpose x[b][nf] (128 x 43000) -> xT[nf][b] (43000 x 128)
// ---------------------------------------------------------------------------
__global__ __launch_bounds__(256) void k_transpose(const float* __restrict__ x,
                                                   float* __restrict__ xT)
{
    __shared__ float tile[64][129];
    const int c0  = blockIdx.x * 64;
    const int tid = threadIdx.x;

    const int j  = tid & 63;
    const int bs = tid >> 6;
    for (int bb = bs; bb < Bn; bb += 4) {
        int c = c0 + j;
        if (c < NFtot) tile[j][bb] = x[(size_t)bb * NFtot + c];
    }
    __syncthreads();

    const int b  = tid & 127;
    for (int jj = (tid >> 7); jj < 64; jj += 2) {
        int c = c0 + jj;
        if (c < NFtot) xT[(size_t)c * Bn + b] = tile[jj][b];
    }
}

// ---------------------------------------------------------------------------
// CSR build
// ---------------------------------------------------------------------------
__global__ void k_zero(int* __restrict__ cnt, int* __restrict__ pos)
{
    int i = blockIdx.x * blockDim.x + threadIdx.x;
    if (i < 4096) { cnt[i] = 0; pos[i] = 0; }
}

__global__ void k_count(const int* __restrict__ ei, const int* __restrict__ et,
                        int* __restrict__ cnt)
{
    int e = blockIdx.x * blockDim.x + threadIdx.x;
    if (e < En) {
        int dst = ei[En + e];
        atomicAdd(&cnt[dst * Rn + et[e]], 1);
    }
}

__global__ __launch_bounds__(1024) void k_scan(const int* __restrict__ cnt,
                                               int* __restrict__ off)
{
    __shared__ int sums[1024];
    int tid = threadIdx.x;
    int base = tid * 4;
    int c[4];
    int ts = 0;
    #pragma unroll
    for (int k = 0; k < 4; ++k) {
        int i = base + k;
        c[k] = (i < Nn * Rn) ? cnt[i] : 0;
        ts += c[k];
    }
    sums[tid] = ts;
    __syncthreads();
    for (int d = 1; d < 1024; d <<= 1) {
        int t = 0;
        if (tid >= d) t = sums[tid - d];
        __syncthreads();
        sums[tid] += t;
        __syncthreads();
    }
    int excl = sums[tid] - ts;
    #pragma unroll
    for (int k = 0; k < 4; ++k) {
        int i = base + k;
        off[i] = excl;
        excl += c[k];
    }
}

__global__ void k_fill(const int* __restrict__ ei, const int* __restrict__ et,
                       const int* __restrict__ off, int* __restrict__ pos,
                       int* __restrict__ csr)
{
    int e = blockIdx.x * blockDim.x + threadIdx.x;
    if (e < En) {
        int src = ei[e];
        int dst = ei[En + e];
        int seg = dst * Rn + et[e];
        int p = atomicAdd(&pos[seg], 1);
        csr[off[seg] + p] = src;
    }
}

// ---------------------------------------------------------------------------
// Kernel 2a: per-(selected dst, relation) mean aggregation, float4 over b.
// grid = 500*4 blocks; 256 thr = 8 f-chunks x 32 b-quads.
// abar[i][r][f][b] = mean over edges of xT[src][f][b].
// ---------------------------------------------------------------------------
__global__ __launch_bounds__(256) void k_agg4(
    const float* __restrict__ xT,
    const int* __restrict__ csr, const int* __restrict__ off,
    const int* __restrict__ cnt, const int* __restrict__ sel,
    float* __restrict__ abar)
{
    __shared__ int srcs[128];

    const int blk = blockIdx.x;
    const int i   = blk >> 2;
    const int r   = blk & 3;
    const int dst = sel[i];
    const int tid = threadIdx.x;
    const int b4  = tid & 31;      // b quad index
    const int fc  = tid >> 5;      // 0..7

    const int seg = dst * Rn + r;
    const int c   = cnt[seg];
    const int o   = off[seg];
    const int cc  = (c < 128) ? c : 128;
    if (tid < cc) srcs[tid] = csr[o + tid];
    __syncthreads();

    const int nk = (fc < 3) ? 6 : 5;   // f = fc + 8k < 43

    float4 acc[6];
    #pragma unroll
    for (int k = 0; k < 6; ++k) acc[k] = make_float4(0.f, 0.f, 0.f, 0.f);

    const float4* xT4 = (const float4*)xT;
    for (int j = 0; j < cc; ++j) {
        const int src = srcs[j];
        const float4* base = xT4 + (size_t)src * (FSn * 32) + (size_t)fc * 32 + b4;
        #pragma unroll
        for (int k = 0; k < 6; ++k) {
            if (k < nk) {
                const float4 v = base[k * 8 * 32];
                acc[k].x += v.x; acc[k].y += v.y; acc[k].z += v.z; acc[k].w += v.w;
            }
        }
    }

    const float inv = (c > 0) ? 1.f / (float)c : 0.f;
    float4* ab4 = (float4*)abar + (size_t)(i * Rn + r) * (FSn * 32) + (size_t)fc * 32 + b4;
    #pragma unroll
    for (int k = 0; k < 6; ++k) {
        if (k < nk) {
            float4 v = acc[k];
            v.x *= inv; v.y *= inv; v.z *= inv; v.w *= inv;
            ab4[k * 8 * 32] = v;
        }
    }
}

// ---------------------------------------------------------------------------
// Kernel 2b: relational transform + root + leaky + final projection.
// grid = 500; 512 thr = 4 f-groups x 128 b. Reads abar + xT (root row).
// ---------------------------------------------------------------------------
__global__ __launch_bounds__(512) void k_trans(
    const float* __restrict__ xT, const float* __restrict__ abar,
    const float* __restrict__ w_rel, const float* __restrict__ w_root,
    const float* __restrict__ b_g,
    const float* __restrict__ w_fin, const float* __restrict__ b_fin,
    const float* __restrict__ la,
    const int* __restrict__ sel,
    float* __restrict__ logitT)
{
    __shared__ float red[FSn + 1][Bn];

    const int i   = blockIdx.x;
    const int dst = sel[i];
    const int tid = threadIdx.x;
    const int fs  = tid >> 7;
    const int b   = tid & 127;

    const int f0 = fs * 11;
    const int nf = (fs == 3) ? 10 : 11;

    float a[5][11];
    #pragma unroll
    for (int rr = 0; rr < 4; ++rr) {
        const float* ap = abar + ((size_t)(i * Rn + rr) * FSn + f0) * Bn + b;
        #pragma unroll
        for (int k = 0; k < 11; ++k)
            a[rr][k] = (k < nf) ? ap[(size_t)k * Bn] : 0.f;
    }
    {
        const float* xp = xT + ((size_t)dst * FSn + f0) * Bn + b;
        #pragma unroll
        for (int k = 0; k < 11; ++k)
            a[4][k] = (k < nf) ? xp[(size_t)k * Bn] : 0.f;
    }

    float accg[FSn];
    #pragma unroll
    for (int g = 0; g < FSn; ++g) accg[g] = 0.f;
    float psum = 0.f;

    #pragma unroll
    for (int k = 0; k < 11; ++k) {
        if (k < nf) {
            const int f = f0 + k;
            #pragma unroll
            for (int rr = 0; rr < 5; ++rr) {
                const float av = a[rr][k];
                const float* wrow = (rr < 4)
                    ? (w_rel + ((size_t)rr * FSn + f) * FSn)
                    : (w_root + (size_t)f * FSn);
                #pragma unroll
                for (int g = 0; g < FSn; ++g) accg[g] += av * wrow[g];
            }
            psum += a[4][k] * w_fin[1 + f];
        }
    }

    if (fs == 3) {
        #pragma unroll
        for (int g = 0; g < FSn; ++g) red[g][b] = accg[g];
        red[FSn][b] = psum;
    }
    __syncthreads();
    if (fs == 2) {
        #pragma unroll
        for (int g = 0; g < FSn; ++g) red[g][b] += accg[g];
        red[FSn][b] += psum;
    }
    __syncthreads();
    if (fs == 1) {
        #pragma unroll
        for (int g = 0; g < FSn; ++g) red[g][b] += accg[g];
        red[FSn][b] += psum;
    }
    __syncthreads();
    if (fs == 0) {
        float logit = b_fin[0] + w_fin[0] * la[(size_t)b * (NSELn + 1) + 1 + i]
                    + psum + red[FSn][b];
        #pragma unroll
        for (int g = 0; g < FSn; ++g) {
            float v = accg[g] + red[g][b] + b_g[g];
            v = (v > 0.f) ? v : 0.01f * v;
            logit += v * w_fin[44 + g];
        }
        logitT[(size_t)i * Bn + b] = logit;
    }
}

// ---------------------------------------------------------------------------
// Kernel 3: softmax over [0, logits(500)] per batch. Block per b.
// ---------------------------------------------------------------------------
__global__ __launch_bounds__(512) void k_softmax(const float* __restrict__ logitT,
                                                 float* __restrict__ out)
{
    __shared__ float red[512];
    const int b   = blockIdx.x;
    const int tid = threadIdx.x;

    const float l = (tid < NSELn) ? logitT[(size_t)tid * Bn + b] : -1e30f;
    red[tid] = l;
    __syncthreads();
    for (int s = 256; s > 0; s >>= 1) {
        if (tid < s) red[tid] = fmaxf(red[tid], red[tid + s]);
        __syncthreads();
    }
    const float m = fmaxf(red[0], 0.f);
    __syncthreads();

    const float e = (tid < NSELn) ? expf(l - m) : 0.f;
    red[tid] = e;
    __syncthreads();
    for (int s = 256; s > 0; s >>= 1) {
        if (tid < s) red[tid] += red[tid + s];
        __syncthreads();
    }
    const float e0  = expf(-m);
    const float inv = 1.f / (red[0] + e0);

    if (tid == 0) out[(size_t)b * (NSELn + 1)] = e0 * inv;
    if (tid < NSELn) out[(size_t)b * (NSELn + 1) + 1 + tid] = e * inv;
}

// ---------------------------------------------------------------------------
extern "C" void kernel_launch(void* const* d_in, const int* in_sizes, int n_in,
                              void* d_out, int out_size, void* d_ws, size_t ws_size,
                              hipStream_t stream)
{
    const float* obs    = (const float*)d_in[0];
    const float* la     = (const float*)d_in[1];
    const float* w_s1   = (const float*)d_in[2];
    const float* b_s1   = (const float*)d_in[3];
    const float* w_s2   = (const float*)d_in[4];
    const float* b_s2   = (const float*)d_in[5];
    const float* w_m1   = (const float*)d_in[6];
    const float* b_m1   = (const float*)d_in[7];
    const float* w_m2   = (const float*)d_in[8];
    const float* b_m2   = (const float*)d_in[9];
    const float* w_rel  = (const float*)d_in[10];
    const float* w_root = (const float*)d_in[11];
    const float* b_g    = (const float*)d_in[12];
    const float* w_fin  = (const float*)d_in[13];
    const float* b_fin  = (const float*)d_in[14];
    const int*   ei     = (const int*)d_in[15];
    const int*   et     = (const int*)d_in[16];
    const int*   sel    = (const int*)d_in[17];
    float*       out    = (float*)d_out;

    // workspace layout (x aliases the front of abar: x is dead before k_agg4
    // writes abar):
    //   abar : 500*4*43*128 = 11,008,000 floats (44 MB); x = first 5,504,000
    //   xT   : 5,504,000 floats (22 MB)
    //   cnt/off/pos : 4096 ints each;  csr : 32000 ints
    //   logitT : 500*128 floats
    float* abar   = (float*)d_ws;
    float* x      = abar;
    float* xT     = abar + 11008000;
    int*   cnt    = (int*)(xT + 5504000);
    int*   offb   = cnt + 4096;
    int*   pos    = offb + 4096;
    int*   csr    = pos + 4096;
    float* logitT = (float*)(csr + 32000);

    hipLaunchKernelGGL(k_zero,  dim3(16),  dim3(256), 0, stream, cnt, pos);
    hipLaunchKernelGGL(k_count, dim3((En + 255) / 256), dim3(256), 0, stream, ei, et, cnt);
    hipLaunchKernelGGL(k_scan,  dim3(1),   dim3(1024), 0, stream, cnt, offb);
    hipLaunchKernelGGL(k_fill,  dim3((En + 255) / 256), dim3(256), 0, stream, ei, et, offb, pos, csr);

    hipLaunchKernelGGL(k_temporal, dim3(Bn, (Nn + 63) / 64), dim3(512), 0, stream,
                       obs, w_s1, b_s1, w_s2, b_s2, w_m1, b_m1, w_m2, b_m2, x);

    hipLaunchKernelGGL(k_transpose, dim3((NFtot + 63) / 64), dim3(256), 0, stream, x, xT);

    hipLaunchKernelGGL(k_agg4, dim3(NSELn * Rn), dim3(256), 0, stream,
                       xT, csr, offb, cnt, sel, abar);

    hipLaunchKernelGGL(k_trans, dim3(NSELn), dim3(512), 0, stream,
                       xT, abar, w_rel, w_root, b_g, w_fin, b_fin, la, sel, logitT);

    hipLaunchKernelGGL(k_softmax, dim3(Bn), dim3(512), 0, stream, logitT, out);
}